// Round 1
// baseline (141.289 us; speedup 1.0000x reference)
//
#include <hip/hip_runtime.h>
#include <math.h>

__device__ __forceinline__ float sigf(float x) { return 1.0f / (1.0f + expf(-x)); }

__global__ __launch_bounds__(256) void decode_kernel(
    const float* __restrict__ in, const float* __restrict__ anchors,
    const float* __restrict__ thresh, const int* __restrict__ casep,
    float* __restrict__ out, int H, int W, float t, long rowBase, int rows)
{
    int tid = blockIdx.x * blockDim.x + threadIdx.x;
    if (tid >= rows) return;

    int a      = tid % 3;
    int spidx  = tid / 3;
    int x      = spidx % W;
    int y      = (spidx / W) % H;
    int b      = spidx / (W * H);
    long HWl   = (long)H * W;

    const float* src = in + ((long)b * 270 + a * 90) * HWl + (long)y * W + x;

    float th      = thresh[0];
    float invCase = 1.0f / (float)(*casep);

    float v0 = src[0];
    float v1 = src[(size_t)1 * HWl];
    float v2 = src[(size_t)2 * HWl];
    float v3 = src[(size_t)3 * HWl];
    float v4 = src[(size_t)4 * HWl];

    float sp = sigf(v0);
    bool  m  = sp > th;

    float A0 = anchors[a * 2 + 0];
    float A1 = anchors[a * 2 + 1];
    float w  = A0 * expf(v3);
    float h  = A1 * expf(v4);
    float s  = sqrtf(w * w + h * h) * invCase;
    float cx = ((float)x + v1) * t;
    float cy = ((float)y + v2) * t;

    float ms = m ? s : 0.0f;   // exact-0 for masked rows; v*s unchanged when m

    float* dst = out + (size_t)(rowBase + tid) * 90;

    float2 o;
    o.x = m ? (float)b : 0.0f;  o.y = m ? sp : 0.0f;  *(float2*)(dst + 0) = o;
    o.x = m ? cx : 0.0f;        o.y = m ? cy : 0.0f;  *(float2*)(dst + 2) = o;
    o.x = m ? w  : 0.0f;        o.y = m ? h  : 0.0f;  *(float2*)(dst + 4) = o;

    // point: k = 6..17, all scaled by s
    #pragma unroll
    for (int j = 0; j < 6; ++j) {
        int k = 6 + 2 * j;
        float p0 = src[(size_t)(k + 0) * HWl];
        float p1 = src[(size_t)(k + 1) * HWl];
        float2 q; q.x = p0 * ms; q.y = p1 * ms;
        *(float2*)(dst + k) = q;
    }

    // seg: k = 18..89, triplets [coord*s, sigmoid, sigmoid]; process 2 triplets/iter
    #pragma unroll
    for (int j = 0; j < 12; ++j) {
        int k = 18 + 6 * j;
        float a0 = src[(size_t)(k + 0) * HWl];
        float a1 = src[(size_t)(k + 1) * HWl];
        float a2 = src[(size_t)(k + 2) * HWl];
        float a3 = src[(size_t)(k + 3) * HWl];
        float a4 = src[(size_t)(k + 4) * HWl];
        float a5 = src[(size_t)(k + 5) * HWl];
        float2 q;
        q.x = a0 * ms;              q.y = m ? sigf(a1) : 0.0f;  *(float2*)(dst + k + 0) = q;
        q.x = m ? sigf(a2) : 0.0f;  q.y = a3 * ms;              *(float2*)(dst + k + 2) = q;
        q.x = m ? sigf(a4) : 0.0f;  q.y = m ? sigf(a5) : 0.0f;  *(float2*)(dst + k + 4) = q;
    }
}

extern "C" void kernel_launch(void* const* d_in, const int* in_sizes, int n_in,
                              void* d_out, int out_size, void* d_ws, size_t ws_size,
                              hipStream_t stream) {
    const float* in13  = (const float*)d_in[0];
    const float* in26  = (const float*)d_in[1];
    const float* in52  = (const float*)d_in[2];
    const float* anc13 = (const float*)d_in[3];
    const float* anc26 = (const float*)d_in[4];
    const float* anc52 = (const float*)d_in[5];
    const float* th    = (const float*)d_in[6];
    const int*   casep = (const int*)d_in[7];
    float* out = (float*)d_out;

    int B = in_sizes[0] / (270 * 13 * 13);   // 32

    long rows13 = (long)B * 13 * 13 * 3;
    long rows26 = (long)B * 26 * 26 * 3;
    long rows52 = (long)B * 52 * 52 * 3;

    const int BS = 256;
    decode_kernel<<<dim3((rows13 + BS - 1) / BS), dim3(BS), 0, stream>>>(
        in13, anc13, th, casep, out, 13, 13, 32.0f, 0, (int)rows13);
    decode_kernel<<<dim3((rows26 + BS - 1) / BS), dim3(BS), 0, stream>>>(
        in26, anc26, th, casep, out, 26, 26, 16.0f, rows13, (int)rows26);
    decode_kernel<<<dim3((rows52 + BS - 1) / BS), dim3(BS), 0, stream>>>(
        in52, anc52, th, casep, out, 52, 52, 8.0f, rows13 + rows26, (int)rows52);
}

// Round 2
// 96.502 us; speedup vs baseline: 1.4641x; 1.4641x over previous
//
#include <hip/hip_runtime.h>
#include <math.h>

#define BS 64  // one wave per block; 64 rows staged in LDS = 23040 B -> 7 blocks/CU

__device__ __forceinline__ float sigf(float x) { return 1.0f / (1.0f + expf(-x)); }

__global__ __launch_bounds__(BS) void decode_kernel(
    const float* __restrict__ in, const float* __restrict__ anchors,
    const float* __restrict__ thresh, const int* __restrict__ casep,
    float* __restrict__ out, int H, int W, float t, long rowBase, int rows)
{
    __shared__ float lds[BS * 90];

    int blockBase = blockIdx.x * BS;
    int tid = blockBase + threadIdx.x;

    if (tid < rows) {
        int a      = tid % 3;
        int spidx  = tid / 3;
        int x      = spidx % W;
        int y      = (spidx / W) % H;
        int b      = spidx / (W * H);
        long HWl   = (long)H * W;

        const float* src = in + ((long)b * 270 + a * 90) * HWl + (long)y * W + x;

        float th      = thresh[0];
        float invCase = 1.0f / (float)(*casep);

        float v0 = src[0];
        float v1 = src[(size_t)1 * HWl];
        float v2 = src[(size_t)2 * HWl];
        float v3 = src[(size_t)3 * HWl];
        float v4 = src[(size_t)4 * HWl];

        float sp = sigf(v0);
        bool  m  = sp > th;

        float A0 = anchors[a * 2 + 0];
        float A1 = anchors[a * 2 + 1];
        float w  = A0 * expf(v3);
        float h  = A1 * expf(v4);
        float s  = sqrtf(w * w + h * h) * invCase;
        float cx = ((float)x + v1) * t;
        float cy = ((float)y + v2) * t;

        float ms = m ? s : 0.0f;   // exact-0 for masked rows; v*s unchanged when m

        float* dst = lds + threadIdx.x * 90;

        float2 o;
        o.x = m ? (float)b : 0.0f;  o.y = m ? sp : 0.0f;  *(float2*)(dst + 0) = o;
        o.x = m ? cx : 0.0f;        o.y = m ? cy : 0.0f;  *(float2*)(dst + 2) = o;
        o.x = m ? w  : 0.0f;        o.y = m ? h  : 0.0f;  *(float2*)(dst + 4) = o;

        // point: k = 6..17, all scaled by s
        #pragma unroll
        for (int j = 0; j < 6; ++j) {
            int k = 6 + 2 * j;
            float p0 = src[(size_t)(k + 0) * HWl];
            float p1 = src[(size_t)(k + 1) * HWl];
            float2 q; q.x = p0 * ms; q.y = p1 * ms;
            *(float2*)(dst + k) = q;
        }

        // seg: k = 18..89, triplets [coord*s, sigmoid, sigmoid]
        #pragma unroll
        for (int j = 0; j < 12; ++j) {
            int k = 18 + 6 * j;
            float a0 = src[(size_t)(k + 0) * HWl];
            float a1 = src[(size_t)(k + 1) * HWl];
            float a2 = src[(size_t)(k + 2) * HWl];
            float a3 = src[(size_t)(k + 3) * HWl];
            float a4 = src[(size_t)(k + 4) * HWl];
            float a5 = src[(size_t)(k + 5) * HWl];
            float2 q;
            q.x = a0 * ms;              q.y = m ? sigf(a1) : 0.0f;  *(float2*)(dst + k + 0) = q;
            q.x = m ? sigf(a2) : 0.0f;  q.y = a3 * ms;              *(float2*)(dst + k + 2) = q;
            q.x = m ? sigf(a4) : 0.0f;  q.y = m ? sigf(a5) : 0.0f;  *(float2*)(dst + k + 4) = q;
        }
    }

    __syncthreads();

    // Coalesced flush: LDS -> global. Rows are contiguous in the output,
    // so the block's nrows*90 floats are one contiguous span.
    int nrows = rows - blockBase;
    if (nrows > BS) nrows = BS;
    if (nrows <= 0) return;

    size_t gbase = (size_t)(rowBase + blockBase) * 90;
    int nfl = nrows * 90;
    int nf4 = nfl >> 2;                      // float4 chunks (16B-aligned: base mult of 360B w/ even row idx)
    float4* d4 = (float4*)(out + gbase);
    const float4* s4 = (const float4*)lds;
    for (int i = threadIdx.x; i < nf4; i += BS) d4[i] = s4[i];

    int rem = nfl & 3;                        // 0 here (nrows even), guard anyway
    int tail = nf4 << 2;
    if ((int)threadIdx.x < rem) out[gbase + tail + threadIdx.x] = lds[tail + threadIdx.x];
}

extern "C" void kernel_launch(void* const* d_in, const int* in_sizes, int n_in,
                              void* d_out, int out_size, void* d_ws, size_t ws_size,
                              hipStream_t stream) {
    const float* in13  = (const float*)d_in[0];
    const float* in26  = (const float*)d_in[1];
    const float* in52  = (const float*)d_in[2];
    const float* anc13 = (const float*)d_in[3];
    const float* anc26 = (const float*)d_in[4];
    const float* anc52 = (const float*)d_in[5];
    const float* th    = (const float*)d_in[6];
    const int*   casep = (const int*)d_in[7];
    float* out = (float*)d_out;

    int B = in_sizes[0] / (270 * 13 * 13);   // 32

    long rows13 = (long)B * 13 * 13 * 3;
    long rows26 = (long)B * 26 * 26 * 3;
    long rows52 = (long)B * 52 * 52 * 3;

    decode_kernel<<<dim3((rows13 + BS - 1) / BS), dim3(BS), 0, stream>>>(
        in13, anc13, th, casep, out, 13, 13, 32.0f, 0, (int)rows13);
    decode_kernel<<<dim3((rows26 + BS - 1) / BS), dim3(BS), 0, stream>>>(
        in26, anc26, th, casep, out, 26, 26, 16.0f, rows13, (int)rows26);
    decode_kernel<<<dim3((rows52 + BS - 1) / BS), dim3(BS), 0, stream>>>(
        in52, anc52, th, casep, out, 52, 52, 8.0f, rows13 + rows26, (int)rows52);
}

// Round 3
// 89.033 us; speedup vs baseline: 1.5869x; 1.0839x over previous
//
#include <hip/hip_runtime.h>
#include <math.h>

#define BS  64   // one wave per block
#define RPB 32   // rows per block; LDS = 32*90*4 = 11520 B -> 14 blocks/CU

__device__ __forceinline__ float sigf(float x) { return 1.0f / (1.0f + expf(-x)); }

// Row layout: [n, sig(p), cx, cy, w, h, point*12 (all *s), seg*72 (triplets: coord*s, sig, sig)]
// For k>=18: coord iff k%3==0 (18%3==0). Lane h covers k in [45h, 45h+45); k=45h+j,
// (45h+j)%3 == j%3, so "coord iff j%3==0" holds for BOTH lanes. Point region 6..17 is
// lane0-only coords; obj entries 0..5 are lane0 overrides.
template<int H, int W, int T>
__device__ __forceinline__ void decode_level(
    const float* __restrict__ in, const float* __restrict__ anchors,
    float th, float invCase,
    float* __restrict__ out, long gRowBase, int blockBaseL,
    float* __restrict__ lds, int lane)
{
    const int h = lane & 1;
    const int r = lane >> 1;
    const int row = blockBaseL + r;          // rows per level divisible by 32 (B=32)
    const int a   = row % 3;
    const int spi = row / 3;
    const int x   = spi % W;
    const int y   = (spi / W) % H;
    const int b   = spi / (W * H);
    const long HWl = (long)H * W;
    const float* src = in + ((long)b * 270 + a * 90 + 45 * h) * HWl + (long)y * W + x;

    // Load this lane's 45 values (strided by H*W); array form encourages MLP.
    float v[45];
    #pragma unroll
    for (int j = 0; j < 45; ++j) v[j] = src[(size_t)j * HWl];

    // Row scalars — meaningful on even lanes (they hold k=0..4); odd lanes get via shfl.
    float sp = sigf(v[0]);
    bool  m  = sp > th;
    float A0 = anchors[a * 2 + 0], A1 = anchors[a * 2 + 1];
    float w  = A0 * expf(v[3]);
    float hb = A1 * expf(v[4]);
    float s  = sqrtf(w * w + hb * hb) * invCase;
    float cx = ((float)x + v[1]) * (float)T;
    float cy = ((float)y + v[2]) * (float)T;
    float ms = m ? s : 0.0f;
    float mf = m ? 1.0f : 0.0f;
    ms = __shfl(ms, lane & ~1, 64);
    mf = __shfl(mf, lane & ~1, 64);
    const bool mB = mf > 0.5f;

    float* dst = lds + r * 90 + 45 * h;
    #pragma unroll
    for (int j = 0; j < 45; ++j) {
        float val = v[j];
        float rv;
        if (j % 3 == 0)             rv = val * ms;                       // coord both lanes
        else if (j >= 6 && j < 18)  rv = (h == 0) ? val * ms             // point (lane0)
                                                  : (mB ? sigf(val) : 0.0f);
        else                        rv = mB ? sigf(val) : 0.0f;          // sigmoid entries
        dst[j] = rv;
    }
    if (h == 0) {   // obj entries override (lane0's own m/s are valid here)
        dst[0] = m ? (float)b : 0.0f;
        dst[1] = m ? sp       : 0.0f;
        dst[2] = m ? cx       : 0.0f;
        dst[3] = m ? cy       : 0.0f;
        dst[4] = m ? w        : 0.0f;
        dst[5] = m ? hb       : 0.0f;
    }
    __syncthreads();

    // Coalesced flush: 32 rows * 90 floats = 720 float4, lane-contiguous.
    size_t gbase = (size_t)(gRowBase + blockBaseL) * 90;   // multiple of 4 floats (16B)
    float4* d4 = (float4*)(out + gbase);
    const float4* s4 = (const float4*)lds;
    for (int i = lane; i < RPB * 90 / 4; i += BS) d4[i] = s4[i];
}

__global__ __launch_bounds__(BS) void decode_all(
    const float* __restrict__ in13, const float* __restrict__ in26,
    const float* __restrict__ in52,
    const float* __restrict__ anc13, const float* __restrict__ anc26,
    const float* __restrict__ anc52,
    const float* __restrict__ thresh, const int* __restrict__ casep,
    float* __restrict__ out, int nb13, int nb26, long rows13, long rows26)
{
    __shared__ float lds[RPB * 90];
    const int lane = threadIdx.x;
    const float th = thresh[0];
    const float invCase = 1.0f / (float)(*casep);
    const int blk = blockIdx.x;

    if (blk < nb13)
        decode_level<13, 13, 32>(in13, anc13, th, invCase, out, 0,
                                 blk * RPB, lds, lane);
    else if (blk < nb13 + nb26)
        decode_level<26, 26, 16>(in26, anc26, th, invCase, out, rows13,
                                 (blk - nb13) * RPB, lds, lane);
    else
        decode_level<52, 52, 8>(in52, anc52, th, invCase, out, rows13 + rows26,
                                 (blk - nb13 - nb26) * RPB, lds, lane);
}

extern "C" void kernel_launch(void* const* d_in, const int* in_sizes, int n_in,
                              void* d_out, int out_size, void* d_ws, size_t ws_size,
                              hipStream_t stream) {
    const float* in13  = (const float*)d_in[0];
    const float* in26  = (const float*)d_in[1];
    const float* in52  = (const float*)d_in[2];
    const float* anc13 = (const float*)d_in[3];
    const float* anc26 = (const float*)d_in[4];
    const float* anc52 = (const float*)d_in[5];
    const float* th    = (const float*)d_in[6];
    const int*   casep = (const int*)d_in[7];
    float* out = (float*)d_out;

    int B = in_sizes[0] / (270 * 13 * 13);   // 32

    long rows13 = (long)B * 13 * 13 * 3;
    long rows26 = (long)B * 26 * 26 * 3;
    long rows52 = (long)B * 52 * 52 * 3;

    int nb13 = (int)(rows13 / RPB);
    int nb26 = (int)(rows26 / RPB);
    int nb52 = (int)(rows52 / RPB);

    decode_all<<<dim3(nb13 + nb26 + nb52), dim3(BS), 0, stream>>>(
        in13, in26, in52, anc13, anc26, anc52, th, casep, out,
        nb13, nb26, rows13, rows26);
}

// Round 4
// 56.633 us; speedup vs baseline: 2.4948x; 1.5721x over previous
//
#include <hip/hip_runtime.h>
#include <math.h>

#define PX 32            // pixels per block (per wave, shared across 3 anchor-waves)
#define NT 192           // 3 waves: wave id == anchor

__device__ __forceinline__ float sigf(float x) { return 1.0f / (1.0f + expf(-x)); }

// Wave a, lane = (h = lane>>5, p = lane&31): handles row (pixel P0+p, anchor a),
// vector entries k in [45h, 45h+45). For fixed j, the wave's loads form two
// 128B-aligned clusters (channel a*90+45h+j, pixels P0..P0+31). Blocks never
// cross image boundaries, so P0 is 32-aligned within the HW plane.
template<int H, int W, int T, bool F4>
__device__ __forceinline__ void decode_level(
    const float* __restrict__ in, const float* __restrict__ anchors,
    float th, float invCase, float* __restrict__ out, long gRowBase,
    int blkL, float* __restrict__ lds)
{
    constexpr int HW = H * W;
    constexpr int SPANS = (HW + PX - 1) / PX;
    const int b    = blkL / SPANS;
    const int P0   = (blkL % SPANS) * PX;
    const int npix = (HW - P0 < PX) ? (HW - P0) : PX;

    const int a    = threadIdx.x >> 6;     // anchor = wave id
    const int lane = threadIdx.x & 63;
    const int h    = lane >> 5;
    const int p    = lane & 31;

    if (p < npix) {
        const int pix = P0 + p;
        const int x   = pix % W;
        const int y   = pix / W;
        const float* src = in + ((long)b * 270 + a * 90 + 45 * h) * HW + pix;

        float v[45];
        #pragma unroll
        for (int j = 0; j < 45; ++j) v[j] = src[(long)j * HW];

        // Per-row scalars: valid on h==0 lanes (their v[0..4] are channels 0..4).
        float sp = sigf(v[0]);
        bool  m  = sp > th;
        float A0 = anchors[a * 2 + 0], A1 = anchors[a * 2 + 1];
        float w  = A0 * expf(v[3]);
        float hb = A1 * expf(v[4]);
        float s  = sqrtf(w * w + hb * hb) * invCase;
        float cx = ((float)x + v[1]) * (float)T;
        float cy = ((float)y + v[2]) * (float)T;

        float ms = __shfl(m ? s : 0.0f, p, 64);       // broadcast h0 -> h1 partner
        float mf = __shfl(m ? 1.0f : 0.0f, p, 64);
        const bool mB = mf > 0.5f;

        float* dst = lds + (p * 3 + a) * 90 + 45 * h;
        #pragma unroll
        for (int j = 0; j < 45; ++j) {
            float val = v[j];
            // k = 45h + j; coord entries: k%3==0 (== j%3==0), plus point region
            // (k in [6,18), h==0 only) which is all coords scaled by s.
            bool coordAlways = (j % 3 == 0);
            bool pointRegion = (j >= 6 && j < 18);
            float rv;
            if (coordAlways)      rv = val * ms;
            else if (pointRegion) rv = (h == 0) ? val * ms : (mB ? sigf(val) : 0.0f);
            else                  rv = mB ? sigf(val) : 0.0f;
            dst[j] = rv;
        }
        if (h == 0) {   // obj entries 0..5 override (local m/s valid here)
            dst[0] = m ? (float)b : 0.0f;
            dst[1] = m ? sp       : 0.0f;
            dst[2] = m ? cx       : 0.0f;
            dst[3] = m ? cy       : 0.0f;
            dst[4] = m ? w        : 0.0f;
            dst[5] = m ? hb       : 0.0f;
        }
    }
    __syncthreads();

    // Flush npix*3 contiguous rows (full 64B lines; base alignment proven per level).
    const int nfl = npix * 3 * 90;
    const size_t gbase = (size_t)(gRowBase + ((long)b * HW + P0) * 3) * 90;
    if (F4) {
        float4* d4 = (float4*)(out + gbase);
        const float4* s4 = (const float4*)lds;
        for (int i = threadIdx.x; i < (nfl >> 2); i += NT) d4[i] = s4[i];
    } else {
        float2* d2 = (float2*)(out + gbase);
        const float2* s2 = (const float2*)lds;
        for (int i = threadIdx.x; i < (nfl >> 1); i += NT) d2[i] = s2[i];
    }
}

__global__ __launch_bounds__(NT, 3) void decode_all(
    const float* __restrict__ in13, const float* __restrict__ in26,
    const float* __restrict__ in52,
    const float* __restrict__ anc13, const float* __restrict__ anc26,
    const float* __restrict__ anc52,
    const float* __restrict__ thresh, const int* __restrict__ casep,
    float* __restrict__ out, int nblk52, int nblk26, long rows13, long rows26)
{
    __shared__ float lds[PX * 3 * 90];
    const float th = thresh[0];
    const float invCase = 1.0f / (float)(*casep);
    const int blk = blockIdx.x;

    if (blk < nblk52)
        decode_level<52, 52, 8, true>(in52, anc52, th, invCase, out,
                                      rows13 + rows26, blk, lds);
    else if (blk < nblk52 + nblk26)
        decode_level<26, 26, 16, true>(in26, anc26, th, invCase, out,
                                       rows13, blk - nblk52, lds);
    else
        decode_level<13, 13, 32, false>(in13, anc13, th, invCase, out,
                                        0, blk - nblk52 - nblk26, lds);
}

extern "C" void kernel_launch(void* const* d_in, const int* in_sizes, int n_in,
                              void* d_out, int out_size, void* d_ws, size_t ws_size,
                              hipStream_t stream) {
    const float* in13  = (const float*)d_in[0];
    const float* in26  = (const float*)d_in[1];
    const float* in52  = (const float*)d_in[2];
    const float* anc13 = (const float*)d_in[3];
    const float* anc26 = (const float*)d_in[4];
    const float* anc52 = (const float*)d_in[5];
    const float* th    = (const float*)d_in[6];
    const int*   casep = (const int*)d_in[7];
    float* out = (float*)d_out;

    int B = in_sizes[0] / (270 * 13 * 13);   // 32

    long rows13 = (long)B * 13 * 13 * 3;
    long rows26 = (long)B * 26 * 26 * 3;

    int nblk13 = B * ((13 * 13 + PX - 1) / PX);    // 32*6   = 192
    int nblk26 = B * ((26 * 26 + PX - 1) / PX);    // 32*22  = 704
    int nblk52 = B * ((52 * 52 + PX - 1) / PX);    // 32*85  = 2720

    decode_all<<<dim3(nblk52 + nblk26 + nblk13), dim3(NT), 0, stream>>>(
        in13, in26, in52, anc13, anc26, anc52, th, casep, out,
        nblk52, nblk26, rows13, rows26);
}

// Round 5
// 54.519 us; speedup vs baseline: 2.5915x; 1.0388x over previous
//
#include <hip/hip_runtime.h>
#include <math.h>

#define PX 32            // pixels per block (shared across 3 anchor-waves)
#define NT 192           // 3 waves: wave id == anchor
#define HPX 16           // pixels staged per flush phase
#define LROWS (HPX * 3)  // 48 rows in LDS -> 17280 B -> 9 blocks/CU = 27 waves

__device__ __forceinline__ float sigf(float x) { return 1.0f / (1.0f + expf(-x)); }

template<bool F4>
__device__ __forceinline__ void flushLds(const float* __restrict__ lds,
                                         float* __restrict__ outp, int nfl, int tid)
{
    if (F4) {
        float4* d4 = (float4*)outp;
        const float4* s4 = (const float4*)lds;
        for (int i = tid; i < (nfl >> 2); i += NT) d4[i] = s4[i];
        // tails here are even multiples of 4 floats per proof in caller; guard anyway
        int rem = nfl & 3, tail = nfl & ~3;
        if (tid < rem) outp[tail + tid] = lds[tail + tid];
    } else {
        float2* d2 = (float2*)outp;
        const float2* s2 = (const float2*)lds;
        for (int i = tid; i < (nfl >> 1); i += NT) d2[i] = s2[i];
    }
}

// Wave a, lane = (h = lane>>5, p = lane&31): row (pixel P0+p, anchor a), entries
// k in [45h, 45h+45). Per j the wave reads two 128B pixel-clusters (full 64B lines).
// Two-phase LDS staging: pixels [0,16) then [16,32) through a [48][90] buffer.
template<int H, int W, int T, bool F4>
__device__ __forceinline__ void decode_level(
    const float* __restrict__ in, const float* __restrict__ anchors,
    float th, float invCase, float* __restrict__ out, long gRowBase,
    int blkL, float* __restrict__ lds)
{
    constexpr int HW = H * W;
    constexpr int SPANS = (HW + PX - 1) / PX;
    const int b    = blkL / SPANS;
    const int P0   = (blkL % SPANS) * PX;
    const int npix = (HW - P0 < PX) ? (HW - P0) : PX;

    const int tid  = threadIdx.x;
    const int a    = tid >> 6;
    const int lane = tid & 63;
    const int h    = lane >> 5;
    const int p    = lane & 31;
    const bool act = (p < npix);

    float v[45];
    if (act) {
        const int pix = P0 + p;
        const int x   = pix % W;
        const int y   = pix / W;
        const float* src = in + ((long)b * 270 + a * 90 + 45 * h) * HW + pix;

        #pragma unroll
        for (int j = 0; j < 45; ++j) v[j] = src[(long)j * HW];

        // Per-row scalars: valid on h==0 lanes (their v[0..4] are channels 0..4).
        float sp = sigf(v[0]);
        bool  m  = sp > th;
        float A0 = anchors[a * 2 + 0], A1 = anchors[a * 2 + 1];
        float w  = A0 * expf(v[3]);
        float hb = A1 * expf(v[4]);
        float s  = sqrtf(w * w + hb * hb) * invCase;
        float cx = ((float)x + v[1]) * (float)T;
        float cy = ((float)y + v[2]) * (float)T;

        float ms = __shfl(m ? s : 0.0f, p, 64);       // broadcast h0 -> h1 partner
        float mf = __shfl(m ? 1.0f : 0.0f, p, 64);
        const bool mB = mf > 0.5f;

        #pragma unroll
        for (int j = 0; j < 45; ++j) {
            float val = v[j];
            // k = 45h + j; coord iff k%3==0 (== j%3==0); point region k in [6,18)
            // exists only on h==0 and is all coords.
            bool coordAlways = (j % 3 == 0);
            bool pointRegion = (j >= 6 && j < 18);
            if (coordAlways)      v[j] = val * ms;
            else if (pointRegion) v[j] = (h == 0) ? val * ms : (mB ? sigf(val) : 0.0f);
            else                  v[j] = mB ? sigf(val) : 0.0f;
        }
        if (h == 0) {   // obj entries 0..5 override (local m/s valid on h==0)
            v[0] = m ? (float)b : 0.0f;
            v[1] = m ? sp       : 0.0f;
            v[2] = m ? cx       : 0.0f;
            v[3] = m ? cy       : 0.0f;
            v[4] = m ? w        : 0.0f;
            v[5] = m ? hb       : 0.0f;
        }
    }

    const size_t gbase = (size_t)(gRowBase + ((long)b * HW + P0) * 3) * 90;

    // ---- phase A: pixels [0, HPX) ----
    if (act && p < HPX) {
        float* dst = lds + (p * 3 + a) * 90 + 45 * h;
        #pragma unroll
        for (int j = 0; j < 45; ++j) dst[j] = v[j];
    }
    __syncthreads();
    int npixA = npix < HPX ? npix : HPX;
    flushLds<F4>(lds, out + gbase, npixA * 3 * 90, tid);

    // ---- phase B: pixels [HPX, PX) ----
    int npixB = npix - HPX;
    if (npixB > 0) {
        __syncthreads();
        if (act && p >= HPX) {
            float* dst = lds + ((p - HPX) * 3 + a) * 90 + 45 * h;
            #pragma unroll
            for (int j = 0; j < 45; ++j) dst[j] = v[j];
        }
        __syncthreads();
        flushLds<F4>(lds, out + gbase + (size_t)LROWS * 90, npixB * 3 * 90, tid);
    }
}

__global__ __launch_bounds__(NT, 6) void decode_all(
    const float* __restrict__ in13, const float* __restrict__ in26,
    const float* __restrict__ in52,
    const float* __restrict__ anc13, const float* __restrict__ anc26,
    const float* __restrict__ anc52,
    const float* __restrict__ thresh, const int* __restrict__ casep,
    float* __restrict__ out, int nblk52, int nblk26, long rows13, long rows26)
{
    __shared__ float lds[LROWS * 90];
    const float th = thresh[0];
    const float invCase = 1.0f / (float)(*casep);
    const int blk = blockIdx.x;

    if (blk < nblk52)
        decode_level<52, 52, 8, true>(in52, anc52, th, invCase, out,
                                      rows13 + rows26, blk, lds);
    else if (blk < nblk52 + nblk26)
        decode_level<26, 26, 16, true>(in26, anc26, th, invCase, out,
                                       rows13, blk - nblk52, lds);
    else
        decode_level<13, 13, 32, false>(in13, anc13, th, invCase, out,
                                        0, blk - nblk52 - nblk26, lds);
}

extern "C" void kernel_launch(void* const* d_in, const int* in_sizes, int n_in,
                              void* d_out, int out_size, void* d_ws, size_t ws_size,
                              hipStream_t stream) {
    const float* in13  = (const float*)d_in[0];
    const float* in26  = (const float*)d_in[1];
    const float* in52  = (const float*)d_in[2];
    const float* anc13 = (const float*)d_in[3];
    const float* anc26 = (const float*)d_in[4];
    const float* anc52 = (const float*)d_in[5];
    const float* th    = (const float*)d_in[6];
    const int*   casep = (const int*)d_in[7];
    float* out = (float*)d_out;

    int B = in_sizes[0] / (270 * 13 * 13);   // 32

    long rows13 = (long)B * 13 * 13 * 3;
    long rows26 = (long)B * 26 * 26 * 3;

    int nblk13 = B * ((13 * 13 + PX - 1) / PX);    // 32*6   = 192
    int nblk26 = B * ((26 * 26 + PX - 1) / PX);    // 32*22  = 704
    int nblk52 = B * ((52 * 52 + PX - 1) / PX);    // 32*85  = 2720

    decode_all<<<dim3(nblk52 + nblk26 + nblk13), dim3(NT), 0, stream>>>(
        in13, in26, in52, anc13, anc26, anc52, th, casep, out,
        nblk52, nblk26, rows13, rows26);
}